// Round 6
// baseline (273.694 us; speedup 1.0000x reference)
//
#include <hip/hip_runtime.h>

#define SEQn   512
#define BATCHn 4096
#define INn    9
#define HIDn   64
#define OUTn   10
#define ROW1   72          // u16 elems per h-ring row (144 B)
#define U2P    72          // f32 elems per u2 ring row (288 B)

typedef __attribute__((ext_vector_type(4))) float    f32x4;
typedef __attribute__((ext_vector_type(4))) _Float16 f16x4;
typedef _Float16 half2_t __attribute__((ext_vector_type(2)));
typedef unsigned short u16;
typedef unsigned int   u32;

#define MFMA16(A,B,C) __builtin_amdgcn_mfma_f32_16x16x16f16((A),(B),(C),0,0,0)

#if __has_builtin(__builtin_amdgcn_fdot2)
#define DOT2(a,b,c) __builtin_amdgcn_fdot2((a),(b),(c),false)
#else
__device__ __forceinline__ float DOT2(half2_t a, half2_t b, float c){
    return __builtin_fmaf((float)a.x,(float)b.x, __builtin_fmaf((float)a.y,(float)b.y,c));
}
#endif
#define H2(u) __builtin_bit_cast(half2_t, (u))
#define BCI(f) __builtin_bit_cast(int, (f))
#define BCF(i) __builtin_bit_cast(float, (i))

// tanh(y) given x = 2*log2(e)*y  (2*log2e pre-folded into weights/biases)
__device__ __forceinline__ float tanh_pre(float x){
    float e = __builtin_amdgcn_exp2f(x);
    float r = __builtin_amdgcn_rcpf(e + 1.0f);
    return __builtin_fmaf(-2.0f, r, 1.0f);
}
__device__ __forceinline__ u16 f2h(float v){ return __builtin_bit_cast(u16, (_Float16)v); }
__device__ __forceinline__ float h2f(u16 u){ return (float)__builtin_bit_cast(_Float16, u); }
__device__ __forceinline__ f16x4 cvt4(f32x4 a){
    f16x4 r = {(_Float16)a.x, (_Float16)a.y, (_Float16)a.z, (_Float16)a.w};
    return r;
}

// permlane swaps with wait-state padding (CDNA4 VALU->permlane hazard)
__device__ __forceinline__ void pl16(float& a, float& b){
    asm volatile("s_nop 2\n\tv_permlane16_swap_b32 %0, %1\n\ts_nop 2" : "+v"(a), "+v"(b));
}
__device__ __forceinline__ void pl32(float& a, float& b){
    asm volatile("s_nop 2\n\tv_permlane32_swap_b32 %0, %1\n\ts_nop 2" : "+v"(a), "+v"(b));
}

// broadcast: pack own-row h values into pairs (2 quad_perm) then 7 row_ror
// -> 8 pair-regs covering the 16 h values of this lane's 16-lane row.
// Exact index delivery is PROBED at init (h[l]=l), so any quad_perm/ror
// direction convention is absorbed into the weight gather.
__device__ __forceinline__ void bcast8(float hs, u32 R[8]){
    u32 hu = (u32)f2h(hs);
    int d0 = __builtin_amdgcn_update_dpp(0, (int)hu, 0xA0, 0xF, 0xF, true); // quad [0,0,2,2]
    int d1 = __builtin_amdgcn_update_dpp(0, (int)hu, 0xF5, 0xF, 0xF, true); // quad [1,1,3,3]
    u32 base = ((u32)d0 & 0xFFFFu) | ((u32)d1 << 16);
    R[0] = base;
    R[1] = (u32)__builtin_amdgcn_update_dpp(0, (int)base, 0x122, 0xF, 0xF, true);
    R[2] = (u32)__builtin_amdgcn_update_dpp(0, (int)base, 0x124, 0xF, 0xF, true);
    R[3] = (u32)__builtin_amdgcn_update_dpp(0, (int)base, 0x126, 0xF, 0xF, true);
    R[4] = (u32)__builtin_amdgcn_update_dpp(0, (int)base, 0x128, 0xF, 0xF, true);
    R[5] = (u32)__builtin_amdgcn_update_dpp(0, (int)base, 0x12A, 0xF, 0xF, true);
    R[6] = (u32)__builtin_amdgcn_update_dpp(0, (int)base, 0x12C, 0xF, 0xF, true);
    R[7] = (u32)__builtin_amdgcn_update_dpp(0, (int)base, 0x12E, 0xF, 0xF, true);
}

// probe which halves v_permlane16/32_swap exchange. y=0: dst.low<->src.high
// (per 32/64 group); y=1: mirrored; mode=1: unexpected -> certain fallback.
__device__ __forceinline__ void probe_conv(int lane, int& mode, int& y16, int& y32){
    float pa = (float)lane, pb = 1000.f + (float)lane;
    pl16(pa, pb);
    float a0  = BCF(__builtin_amdgcn_readlane(BCI(pa), 0));
    float a16 = BCF(__builtin_amdgcn_readlane(BCI(pa), 16));
    float a32 = BCF(__builtin_amdgcn_readlane(BCI(pa), 32));
    float a48 = BCF(__builtin_amdgcn_readlane(BCI(pa), 48));
    int c16;
    if      (a0==1016.f && a16==16.f   && a32==1048.f && a48==48.f)   c16 = 0;
    else if (a0==0.f    && a16==1000.f && a32==32.f   && a48==1032.f) c16 = 1;
    else c16 = 2;
    float qa = (float)lane, qb = 1000.f + (float)lane;
    pl32(qa, qb);
    float b0  = BCF(__builtin_amdgcn_readlane(BCI(qa), 0));
    float b32 = BCF(__builtin_amdgcn_readlane(BCI(qa), 32));
    int c32;
    if      (b0==1032.f && b32==32.f)   c32 = 0;
    else if (b0==0.f    && b32==1000.f) c32 = 1;
    else c32 = 2;
    mode = (c16 <= 1 && c32 <= 1) ? 0 : 1;
    y16 = (c16 == 1); y32 = (c32 == 1);
}

// weights gathered against PROBED broadcast indices; output-row permutation
// j -> j ^ y16 ^ (y32<<1) compensates the permlane half conventions.
__device__ __forceinline__ void load_wcal(const float* __restrict__ W, int n, float s,
                                          int mode, int y16, int y32, int lane,
                                          half2_t wr[4][8]){
    u32 Rp[8];
    bcast8((float)lane, Rp);
#pragma unroll
    for (int m = 0; m < 8; ++m){
        int ke = ((int)h2f((u16)(Rp[m] & 0xFFFFu))) & 63;
        int ko = ((int)h2f((u16)(Rp[m] >> 16)))     & 63;
#pragma unroll
        for (int j = 0; j < 4; ++j){
            int jj = (mode == 0) ? (j ^ y16 ^ (y32 << 1)) : j;
            const float* row = W + (n + 16*jj)*HIDn;
            wr[j][m] = half2_t{(_Float16)(row[ke]*s), (_Float16)(row[ko]*s)};
        }
    }
}

// In-register 64x64 matvec, zero LDS stages in mode 0:
// bcast(DPP) -> 32 DOT2 -> 2x permlane16_swap + permlane32_swap butterfly.
// mode 1 fallback: ds_swizzle xor16 + select + ds_bpermute (certain semantics).
__device__ __forceinline__ float matvec_rr(float hs, const half2_t wr[4][8],
                                           int mode, int lane){
    u32 R[8];
    bcast8(hs, R);
    float a[4];
#pragma unroll
    for (int j = 0; j < 4; ++j){
        float sA = DOT2(H2(R[0]), wr[j][0], 0.f);
        sA = DOT2(H2(R[1]), wr[j][1], sA);
        sA = DOT2(H2(R[2]), wr[j][2], sA);
        sA = DOT2(H2(R[3]), wr[j][3], sA);
        float sB = DOT2(H2(R[4]), wr[j][4], 0.f);
        sB = DOT2(H2(R[5]), wr[j][5], sB);
        sB = DOT2(H2(R[6]), wr[j][6], sB);
        sB = DOT2(H2(R[7]), wr[j][7], sB);
        a[j] = sA + sB;
    }
    if (mode == 0){
        pl16(a[1], a[0]); float S1 = a[1] + a[0];   // per-row: out [n+16*(g&1)] partials
        pl16(a[3], a[2]); float S2 = a[3] + a[2];   // per-row: out [n+32+16*(g&1)]
        pl32(S2, S1);
        return S1 + S2;                             // y[own lane], all four rows
    } else {
#pragma unroll
        for (int j = 0; j < 4; ++j){                // xor16: rows 0<->1, 2<->3
            int t = __builtin_amdgcn_ds_swizzle(BCI(a[j]), 0x401F);
            a[j] += BCF(t);
        }
        int g = (lane >> 4) & 3;
        float s01 = (g & 1) ? a[1] : a[0];
        float s23 = (g & 1) ? a[3] : a[2];
        float vs  = (g & 2) ? s23 : s01;            // a[g]
        float vc  = (g & 2) ? s01 : s23;            // a[g^2], exported cross-half
        int t = __builtin_amdgcn_ds_bpermute((lane ^ 32) << 2, BCI(vc));
        return vs + BCF(t);
    }
}

// 4-wave pipeline, watermark chain wm[0](h1)->wm[1](u2)->wm[2](h2)->wm[3](fc):
//   wave0: h1 chain, in-register matvec; writes ring1 only for wave2
//   wave2: u2 = K*(Wih1 h1 + b2) MFMA batches of 16 -> u2r
//   wave1: h2 chain (u2 reg-double-buffered); writes ring2 only for wave3
//   wave3: FC MFMA batches of 16 -> out
// All spins bounded (a protocol bug degrades to wrong answer, not a hang).
extern "C" __global__ __launch_bounds__(256, 1)
void rnn_lastrow(const float* __restrict__ x,
                 const float* __restrict__ Wih0, const float* __restrict__ Whh0,
                 const float* __restrict__ bih0, const float* __restrict__ bhh0,
                 const float* __restrict__ Wih1, const float* __restrict__ Whh1,
                 const float* __restrict__ bih1, const float* __restrict__ bhh1,
                 const float* __restrict__ Wfc,  const float* __restrict__ bfc,
                 float* __restrict__ out)
{
    __shared__ __align__(16) u16   xl16[SEQn*16];    // x[:,4095,:] f16, rows padded to 16
    __shared__ __align__(16) float u2r[64*U2P];      // u2 ring, 64 slots
    __shared__ __align__(16) u16   ring1[64*ROW1];   // h1 history (f16) for wave2
    __shared__ __align__(16) u16   ring2[64*ROW1];   // h2 history (f16) for wave3
    __shared__ u32 wm[4];

    const int tid  = threadIdx.x;
    const int w    = tid >> 6;
    const int lane = tid & 63;
    const int g    = lane >> 4;
    const int n    = lane & 15;
    volatile u32* vwm = wm;
    const float K = 2.8853900817779268f;   // 2*log2(e)

    for (int idx = tid; idx < SEQn*16; idx += 256){
        int t = idx >> 4, j = idx & 15;
        float v = (j < INn) ? x[((long)t*BATCHn + (BATCHn-1))*INn + j] : 0.f;
        xl16[idx] = f2h(v);
    }
    for (int idx = tid; idx < 64*ROW1; idx += 256){ ring1[idx] = 0; ring2[idx] = 0; }
    if (tid < 4) wm[tid] = 0u;
    __syncthreads();

    if (w == 0){
        // ---------------- wave0: h1 chain ----------------
        int mode, y16, y32;
        probe_conv(lane, mode, y16, y32);
        half2_t wr0[4][8];
        load_wcal(Whh0, n, K, mode, y16, y32, lane, wr0);
        half2_t wx[5];
        {
            const float* wxr = Wih0 + lane*INn;
#pragma unroll
            for (int q = 0; q < 4; ++q)
                wx[q] = half2_t{(_Float16)(wxr[2*q]*K), (_Float16)(wxr[2*q+1]*K)};
            wx[4] = half2_t{(_Float16)(wxr[8]*K), (_Float16)0.f};
        }
        const float b1 = (bih0[lane] + bhh0[lane]) * K;
        float hs = 0.f;
        uint4 xa_c; u32 xb_c;
        { const u32* xr = (const u32*)(xl16); xa_c = *(const uint4*)xr; xb_c = xr[4]; }

        for (int p = 0; p < SEQn; ++p){
            if ((p & 15) == 0 && p){
                asm volatile("s_waitcnt lgkmcnt(0)" ::: "memory");
                vwm[0] = (u32)p;
                int guard = 1 << 20;   // ring1 space: need u2 progress wm[1] >= p-48
                while ((vwm[1] + 48u < (u32)p) && --guard) __builtin_amdgcn_s_sleep(2);
                asm volatile("" ::: "memory");
            }
            const u32* xr = (const u32*)(xl16 + ((p+1) & (SEQn-1))*16);  // prefetch x[p+1]
            uint4 xa_n = *(const uint4*)xr;
            u32  xb_n  = xr[4];
            float u1 = b1;
            u1 = DOT2(H2(xa_c.x), wx[0], u1);
            u1 = DOT2(H2(xa_c.y), wx[1], u1);
            u1 = DOT2(H2(xa_c.z), wx[2], u1);
            u1 = DOT2(H2(xa_c.w), wx[3], u1);
            u1 = DOT2(H2(xb_c),   wx[4], u1);
            float z = matvec_rr(hs, wr0, mode, lane);
            hs = tanh_pre(z + u1);
            ring1[(p & 63)*ROW1 + lane] = f2h(hs);
            xa_c = xa_n; xb_c = xb_n;
        }
        asm volatile("s_waitcnt lgkmcnt(0)" ::: "memory");
        vwm[0] = (u32)SEQn;
    } else if (w == 2){
        // ---------------- wave2: u2 batches (MFMA) ----------------
        f16x4 wi1[4][4]; f32x4 b2f[4];
#pragma unroll
        for (int r = 0; r < 4; ++r){
            f32x4 bi1 = *(const f32x4*)&bih1[16*r + 4*g];
            f32x4 bh1 = *(const f32x4*)&bhh1[16*r + 4*g];
            b2f[r] = (bi1 + bh1) * K;
#pragma unroll
            for (int c = 0; c < 4; ++c){
                f32x4 a1 = *(const f32x4*)&Wih1[(16*r + n)*HIDn + 16*c + 4*g];
                wi1[r][c] = cvt4(a1 * K);   // A-frag: lane holds A[m=n][k=16c+4g+i]
            }
        }
        for (int b = 1; b <= 32; ++b){
            int t0 = 16*b;                 // computes u2[t0-16 .. t0)
            int guard = 1 << 20;
            while ((vwm[0] < (u32)t0) && --guard) __builtin_amdgcn_s_sleep(2);
            guard = 1 << 20;               // u2r space: need wave1 wm[2] >= t0-64
            while ((vwm[2] + 64u < (u32)t0) && --guard) __builtin_amdgcn_s_sleep(2);
            asm volatile("" ::: "memory");
            f16x4 B[4];
#pragma unroll
            for (int c = 0; c < 4; ++c)    // B[k][nn] = h1[t0-16+nn][k]
                B[c] = *(const f16x4*)&ring1[((t0-16+n) & 63)*ROW1 + 16*c + 4*g];
            f32x4 D[4];
#pragma unroll
            for (int r = 0; r < 4; ++r) D[r] = b2f[r];
#pragma unroll
            for (int c = 0; c < 4; ++c)
#pragma unroll
                for (int r = 0; r < 4; ++r)
                    D[r] = MFMA16(wi1[r][c], B[c], D[r]);
            int t = (t0 - 16 + n) & 63;    // D[m][nn]: lane holds rows 16r+4g+i, col nn=n
#pragma unroll
            for (int r = 0; r < 4; ++r)
                *(f32x4*)&u2r[t*U2P + 16*r + 4*g] = D[r];
            asm volatile("s_waitcnt lgkmcnt(0)" ::: "memory");
            vwm[1] = (u32)t0;
        }
    } else if (w == 1){
        // ---------------- wave1: h2 chain ----------------
        int mode, y16, y32;
        probe_conv(lane, mode, y16, y32);
        half2_t wr1[4][8];
        load_wcal(Whh1, n, K, mode, y16, y32, lane, wr1);
        float hs2 = 0.f;
        float u2c = 0.f;
        for (int c = 0; c < SEQn; ++c){
            if ((c & 15) == 0){
                asm volatile("s_waitcnt lgkmcnt(0)" ::: "memory");
                vwm[2] = (u32)c;
                u32 need = (c + 17 <= SEQn) ? (u32)(c + 17) : (u32)SEQn;
                int guard = 1 << 20;
                while ((vwm[1] < need) && --guard) __builtin_amdgcn_s_sleep(2);
                guard = 1 << 20;           // ring2 space: need FC progress wm[3] >= c-48
                while ((vwm[3] + 48u < (u32)c) && --guard) __builtin_amdgcn_s_sleep(2);
                asm volatile("" ::: "memory");
                if (c == 0) u2c = u2r[lane];
            }
            float u2n = u2r[((c+1) & 63)*U2P + lane];   // prefetch u2[c+1]
            float z = matvec_rr(hs2, wr1, mode, lane);
            hs2 = tanh_pre(z + u2c);
            ring2[(c & 63)*ROW1 + lane] = f2h(hs2);
            u2c = u2n;
        }
        asm volatile("s_waitcnt lgkmcnt(0)" ::: "memory");
        vwm[2] = (u32)SEQn;
    } else {
        // ---------------- wave3: FC batches (MFMA) ----------------
        f16x4 wfcA[4]; f32x4 bfcf;
        {
            int mrow = (n < OUTn) ? n : (OUTn - 1);   // clamp pad rows (never stored)
#pragma unroll
            for (int c = 0; c < 4; ++c)
                wfcA[c] = cvt4(*(const f32x4*)&Wfc[mrow*HIDn + 16*c + 4*g]);  // unscaled
            int o0 = 4*g;
            bfcf.x = (o0+0 < OUTn) ? bfc[o0+0] : 0.f;
            bfcf.y = (o0+1 < OUTn) ? bfc[o0+1] : 0.f;
            bfcf.z = (o0+2 < OUTn) ? bfc[o0+2] : 0.f;
            bfcf.w = (o0+3 < OUTn) ? bfc[o0+3] : 0.f;
        }
        for (int b = 1; b <= 32; ++b){
            int f0 = 16*b;                 // FC[f0-16 .. f0)
            int guard = 1 << 20;
            while ((vwm[2] < (u32)f0) && --guard) __builtin_amdgcn_s_sleep(2);
            asm volatile("" ::: "memory");
            f16x4 B[4];
#pragma unroll
            for (int c = 0; c < 4; ++c)    // B[k][nn] = h2[f0-16+nn][k]
                B[c] = *(const f16x4*)&ring2[((f0-16+n) & 63)*ROW1 + 16*c + 4*g];
            f32x4 D = bfcf;
#pragma unroll
            for (int c = 0; c < 4; ++c)
                D = MFMA16(wfcA[c], B[c], D);
            int t = f0 - 16 + n;           // lane stores FC[t][o=4g+i]
            float* o = out + t*OUTn + 4*g;
            if (g < 2){ o[0] = D.x; o[1] = D.y; o[2] = D.z; o[3] = D.w; }
            else if (g == 2){ o[0] = D.x; o[1] = D.y; }
            asm volatile("s_waitcnt lgkmcnt(0)" ::: "memory");
            vwm[3] = (u32)f0;
        }
    }
}

extern "C" void kernel_launch(void* const* d_in, const int* in_sizes, int n_in,
                              void* d_out, int out_size, void* d_ws, size_t ws_size,
                              hipStream_t stream){
    rnn_lastrow<<<dim3(1), dim3(256), 0, stream>>>(
        (const float*)d_in[0],
        (const float*)d_in[1], (const float*)d_in[2],
        (const float*)d_in[3], (const float*)d_in[4],
        (const float*)d_in[5], (const float*)d_in[6],
        (const float*)d_in[7], (const float*)d_in[8],
        (const float*)d_in[9], (const float*)d_in[10],
        (float*)d_out);
}